// Round 6
// baseline (275.681 us; speedup 1.0000x reference)
//
#include <hip/hip_runtime.h>

#define S_LEN 2048

typedef float f32x4 __attribute__((ext_vector_type(4)));

__device__ __forceinline__ float rlane(float v, int l) {
    return __int_as_float(__builtin_amdgcn_readlane(__float_as_int(v), l));
}

template<int CTRL, int RM>
__device__ __forceinline__ float dpp_add(float v) {
    int t = __builtin_amdgcn_update_dpp(0, __float_as_int(v), CTRL, RM, 0xF, true);
    return v + __int_as_float(t);
}
// sum across 64 lanes -> uniform scalar, VALU-only.
__device__ __forceinline__ float wave_sum(float v) {
    v = dpp_add<0x111, 0xF>(v);  // row_shr:1
    v = dpp_add<0x112, 0xF>(v);  // row_shr:2
    v = dpp_add<0x114, 0xF>(v);  // row_shr:4
    v = dpp_add<0x118, 0xF>(v);  // row_shr:8
    v = dpp_add<0x142, 0xA>(v);  // row_bcast:15
    v = dpp_add<0x143, 0xC>(v);  // row_bcast:31
    return rlane(v, 63);
}
// wavefront shift right by 1: lane l <- lane l-1, lane 0 <- 0 (bound_ctrl)
__device__ __forceinline__ float wfshr1(float v) {
    int t = __builtin_amdgcn_update_dpp(0, __float_as_int(v), 0x138, 0xF, 0xF, true);
    return __int_as_float(t);
}

#if __has_builtin(__builtin_amdgcn_exp2f)
#define EXP2F(x) __builtin_amdgcn_exp2f(x)
#else
#define EXP2F(x) exp2f(x)
#endif
#if __has_builtin(__builtin_amdgcn_logf)
#define LOG2F(x) __builtin_amdgcn_logf(x)
#else
#define LOG2F(x) __log2f(x)
#endif

// ============================ setup kernel (1 wave) ============================
// Computes the conv coefficients (validated r1-r5) and writes to workspace:
//   ws[0..4096)    rotA: quad-major circulant of K*alpha, lags<4 zeroed
//   ws[4096..8192) rotB: quad-major circulant of TRUE beta, lags<4 zeroed
//                  (sigma kept in log2-domain: K*LN2 = 1 makes beta coeffs true-scale)
//   ws[8192+l]     gpre[l] = K*Gamma_{l+1} (chunk-0 lane-dependent Gamma)
//   ws[8256] ginf; ws[8257..8261) b0..b3 (true beta); ws[8261..8265) K*alpha_{0..3}
__global__ __launch_bounds__(64) void garch_setup(
    const float* __restrict__ Wih, const float* __restrict__ bih,
    const float* __restrict__ Whh, const float* __restrict__ bhh,
    const float* __restrict__ fcw, const float* __restrict__ fcb,
    float* __restrict__ ws)
{
    const int lane = threadIdx.x;
    __shared__ __align__(16) float ub[64];
    __shared__ float alpS[64], betS[64];

    float wr[64];
#pragma unroll
    for (int k = 0; k < 64; ++k) wr[k] = Whh[k * 64 + lane];   // W[k][lane]

    const float w0l = Wih[lane * 2], w1l = Wih[lane * 2 + 1];
    const float bl = bih[lane] + bhh[lane];
    const float fl = fcw[lane];
    const float Kc = 1.44269504088896340736f;   // log2(e)

    float alpv = 0.f, betv = 0.f;
    const float A0  = Kc * wave_sum(fl * w0l);
    const float b0t = wave_sum(fl * w1l);
    const float C   = Kc * (wave_sum(fl * bl) + fcb[0]);
    alpv = (lane == 0) ? A0 : alpv;
    betv = (lane == 0) ? b0t : betv;
    float gpre = C, ginf = C;

    ub[lane] = fl;
    asm volatile("" ::: "memory");
    const f32x4* uq4 = (const f32x4*)ub;
    float u;
    {
        float n0 = 0.f, n1 = 0.f, n2 = 0.f, n3 = 0.f;
#pragma unroll
        for (int q = 0; q < 16; ++q) {
            const f32x4 uq = uq4[q];
            n0 = fmaf(wr[4 * q + 0], uq.x, n0);
            n1 = fmaf(wr[4 * q + 1], uq.y, n1);
            n2 = fmaf(wr[4 * q + 2], uq.z, n2);
            n3 = fmaf(wr[4 * q + 3], uq.w, n3);
        }
        u = (n0 + n1) + (n2 + n3);
    }
#pragma unroll 1
    for (int i = 1; i < 64; ++i) {
        const float daK = Kc * wave_sum(u * w0l);
        const float dbT = wave_sum(u * w1l);          // TRUE beta_i
        const float dgK = Kc * wave_sum(u * bl);      // K*g_{i-1}
        alpv = (lane == i) ? daK : alpv;
        betv = (lane == i) ? dbT : betv;
        gpre += (lane >= i) ? dgK : 0.f;
        ginf += dgK;
        ub[lane] = u;
        asm volatile("" ::: "memory");
        float n0 = 0.f, n1 = 0.f, n2 = 0.f, n3 = 0.f;
#pragma unroll
        for (int q = 0; q < 16; ++q) {
            const f32x4 uq = uq4[q];
            n0 = fmaf(wr[4 * q + 0], uq.x, n0);
            n1 = fmaf(wr[4 * q + 1], uq.y, n1);
            n2 = fmaf(wr[4 * q + 2], uq.z, n2);
            n3 = fmaf(wr[4 * q + 3], uq.w, n3);
        }
        u = (n0 + n1) + (n2 + n3);
    }
    alpS[lane] = alpv;
    betS[lane] = betv;
    asm volatile("" ::: "memory");   // same-wave DS ordering

    for (int f = lane; f < 4096; f += 64) {
        const int w = f & 3, l = (f >> 2) & 63, q = f >> 8;
        const int m = (l - (4 * q + w)) & 63;
        ws[f]        = (m < 4) ? 0.f : alpS[m];
        ws[4096 + f] = (m < 4) ? 0.f : betS[m];
    }
    ws[8192 + lane] = gpre;
    if (lane < 4) {
        ws[8257 + lane] = betS[lane];   // b0..b3 (true beta)
        ws[8261 + lane] = alpS[lane];   // K*alpha_0..3 (E4 FIR taps)
    }
    if (lane == 0) ws[8256] = ginf;
}

// ============================ main kernel ============================
// Segment-parallel decode: wave (row, p) computes steps of chunks [8p, 8p+8),
// with one warm-up chunk (8p-1) started from zero sigma-history. The sigma
// error-propagation eigenvalue is ~rho(W)+O(beta) ~ 0.6 -> warm-up error decays
// 0.6^64 ~ 1e-14: exact to fp32. E-side of the warm-up is EXACT (masked circulant
// init from chunk 8p-2's e^2 + E4 FIR). 8192 waves -> full 32-wave/CU occupancy;
// alpha/beta circulants live in block-shared LDS (r3's conflict-free quad layout)
// to keep VGPRs ~64.
__attribute__((amdgpu_flat_work_group_size(512, 512)))
__attribute__((amdgpu_waves_per_eu(6, 8)))
__global__ void garch_main(
    const float* __restrict__ res, const float* __restrict__ ws,
    float* __restrict__ out)
{
    __shared__ __align__(16) float rot[8192];   // [0,4096) alpha', [4096,8192) beta

    const int tid = threadIdx.x;
    const int lane = tid & 63;
    const int wv = tid >> 6;

    {   // stage tables
        const f32x4* src = (const f32x4*)ws;
        f32x4* dst = (f32x4*)rot;
        for (int i = tid; i < 2048; i += 512) dst[i] = src[i];
    }
    __syncthreads();

    const int gw = blockIdx.x * 8 + wv;     // 0..8191
    const int row_i = gw >> 2;
    const int p = gw & 3;
    const float* __restrict__ row  = res + (size_t)row_i * S_LEN;
    float* __restrict__       orow = out + (size_t)row_i * S_LEN;

    // wave-uniform scalars (uniform address -> s_load)
    const float ginf = ws[8256];
    const float b0 = ws[8257], b1 = ws[8258], b2 = ws[8259], b3 = ws[8260];
    const float aA0 = ws[8261], aA1 = ws[8262], aA2 = ws[8263], aA3 = ws[8264];
    const float Kc  = 1.44269504088896340736f;
    const float LN2 = 0.69314718055994530942f;

// E4 FIR: DST[l] = sum_{m=0..3} K*alpha_m * e2[l-m], boundary via P61..P63
#define E4BUILD(DST, EQ, P61, P62, P63) { \
    const float s1_ = wfshr1(EQ); \
    const float s2_ = wfshr1(s1_); \
    const float s3_ = wfshr1(s2_); \
    float e4_ = aA0 * (EQ); \
    e4_ = fmaf(aA1, s1_, e4_); \
    e4_ = fmaf(aA2, s2_, e4_); \
    e4_ = fmaf(aA3, s3_, e4_); \
    const float f0_ = fmaf(aA1, (P63), fmaf(aA2, (P62), aA3 * (P61))); \
    const float f1_ = fmaf(aA2, (P63), aA3 * (P62)); \
    const float f2_ = aA3 * (P63); \
    e4_ = (lane == 0) ? e4_ + f0_ : e4_; \
    e4_ = (lane == 1) ? e4_ + f1_ : e4_; \
    e4_ = (lane == 2) ? e4_ + f2_ : e4_; \
    (DST) = e4_; }

    const f32x4* rotA4 = (const f32x4*)rot;
    const f32x4* rotB4 = (const f32x4*)(rot + 4096);

    float acc, sigK, carry, eqC, eqN, ldn, e4N;
    float vout = 0.f, var = 0.f;
    int c0;

    if (p == 0) {
        // sigma0 = var(row, ddof=1)
        float s1 = 0.f, s2 = 0.f;
#pragma unroll 8
        for (int i = 0; i < S_LEN / 64; ++i) {
            const float x = row[i * 64 + lane];
            s1 += x;
            s2 = fmaf(x, x, s2);
        }
        s1 = wave_sum(s1);
        s2 = wave_sum(s2);
        const float mean = s1 * (1.0f / S_LEN);
        var = (s2 - s1 * mean) * (1.0f / (S_LEN - 1));
        sigK = Kc * var;              // log2-domain sigma_0
        carry = sigK;

        const float e0 = row[lane], e1 = row[64 + lane];
        eqC = e0 * e0;
        eqN = e1 * e1;
        ldn = row[128 + lane];
        float e4C;
        E4BUILD(e4C, eqC, 0.f, 0.f, 0.f);
        acc = ws[8192 + lane] + e4C;  // gpre + FIR(chunk 0)
        {
            const float p63 = rlane(eqC, 63), p62 = rlane(eqC, 62), p61 = rlane(eqC, 61);
            E4BUILD(e4N, eqN, p61, p62, p63);
        }
        c0 = 0;
    } else {
        const int cw = 8 * p - 1;     // warm-up chunk
        const float eP = row[(cw - 1) * 64 + lane];
        const float eC = row[cw * 64 + lane];
        const float eN = row[(cw + 1) * 64 + lane];
        const float eqP = eP * eP;
        eqC = eC * eC;
        eqN = eN * eN;
        ldn = row[(cw + 2) * 64 + lane];
        {
            const float p63 = rlane(eqP, 63), p62 = rlane(eqP, 62), p61 = rlane(eqP, 61);
            float e4C;
            E4BUILD(e4C, eqC, p61, p62, p63);
            acc = ginf + e4C;
        }
        // exact alpha wrap-init from chunk cw-1: acc += sum_{j>lane} a'_{(lane-j)&63} e2P_j
#pragma unroll
        for (int q = 0; q < 16; ++q) {
            const f32x4 aqv = rotA4[q * 64 + lane];
#pragma unroll
            for (int w = 0; w < 4; ++w) {
                const int j = 4 * q + w;
                const float cf = (j > lane) ? aqv[w] : 0.f;
                acc = fmaf(cf, rlane(eqP, j), acc);
            }
        }
        {
            const float p63 = rlane(eqC, 63), p62 = rlane(eqC, 62), p61 = rlane(eqC, 61);
            E4BUILD(e4N, eqN, p61, p62, p63);
        }
        sigK = 0.f;                   // zero sigma-history (decays in warm-up)
        carry = 0.f;
        c0 = cw;
    }

    float pre = rlane(acc, 0);
    float bp  = rlane(acc, 1);
    float xb  = rlane(acc, 2);
    const int rotaddr = ((lane + 63) & 63) << 2;
    const int NCC = (p == 0) ? 8 : 9;

    // prime group-0 coefficient quads
    f32x4 aq0 = rotA4[lane],      aq1 = rotA4[64 + lane];
    f32x4 bq0 = rotB4[lane],      bq1 = rotB4[64 + lane];

#pragma unroll 1
    for (int cc = 0; cc < NCC; ++cc) {
        const int c = c0 + cc;
        const float sigchunk = carry;   // K-domain sigma_{64c}

#pragma unroll 1
        for (int jg = 0; jg < 8; ++jg) {
            const int ng = ((jg + 1) & 7) << 1;
            const f32x4 naq0 = rotA4[ng * 64 + lane];
            const f32x4 naq1 = rotA4[(ng + 1) * 64 + lane];
            const f32x4 nbq0 = rotB4[ng * 64 + lane];
            const f32x4 nbq1 = rotB4[(ng + 1) * 64 + lane];
#pragma unroll
            for (int k = 0; k < 8; ++k) {
                const int j = (jg << 3) + k;
                const float ash = (k < 4) ? aq0[k] : aq1[k - 4];
                const float bsh = (k < 4) ? bq0[k] : bq1[k - 4];
                const float e2j = rlane(eqC, j);
                const float xp = fmaf(b0, sigK, pre);     // on-chain
                acc = fmaf(bsh, sigK, acc);               // sigma lags >=4
                acc = fmaf(ash, e2j, acc);                // e2 lags >=4
                const bool mine = (lane == j);
                acc = mine ? ginf : acc;                  // reset-at-consume
                float t = rlane(acc, (j + 3) & 63);       // hoisted 3 iters
                if (jg == 7) { if (k >= 5) t += rlane(e4N, k - 5); }
                pre = fmaf(b1, sigK, bp);
                bp  = fmaf(b2, sigK, xb);
                xb  = fmaf(b3, sigK, t);
                const float mx = fmaxf(xp, 0.f);
                const float ee = EXP2F(-__builtin_fabsf(xp));
                const float lg = LOG2F(1.0f + ee);
                sigK = mx + lg;                           // log2-domain softplus
                vout = mine ? sigK : vout;
            }
            aq0 = naq0; aq1 = naq1; bq0 = nbq0; bq1 = nbq1;
        }

        if ((p == 0) || (cc > 0)) {    // warm-up chunk not stored
            const float rotv = __int_as_float(
                __builtin_amdgcn_ds_bpermute(rotaddr, __float_as_int(vout)));
            const float sv = (lane == 0) ? sigchunk : rotv;
            float outv = fmaf(sv, LN2, 1e-6f);
            if (p == 0 && cc == 0 && lane == 0) outv = var;   // t=0: exact variance
            orow[(c << 6) + lane] = outv;
        }
        carry = rlane(vout, 63);

        // advance to next chunk
        acc += e4N;
        const float p63 = rlane(eqN, 63), p62 = rlane(eqN, 62), p61 = rlane(eqN, 61);
        eqC = eqN;
        eqN = ldn * ldn;
        const int nc = (c + 3 < 32) ? (c + 3) : 31;
        ldn = row[nc * 64 + lane];
        E4BUILD(e4N, eqN, p61, p62, p63);
    }
#undef E4BUILD
}

extern "C" void kernel_launch(void* const* d_in, const int* in_sizes, int n_in,
                              void* d_out, int out_size, void* d_ws, size_t ws_size,
                              hipStream_t stream) {
    const float* res = (const float*)d_in[0];
    const float* Wih = (const float*)d_in[1];
    const float* bih = (const float*)d_in[2];
    const float* Whh = (const float*)d_in[3];
    const float* bhh = (const float*)d_in[4];
    const float* fcw = (const float*)d_in[5];
    const float* fcb = (const float*)d_in[6];
    float* out = (float*)d_out;
    float* ws  = (float*)d_ws;

    hipLaunchKernelGGL(garch_setup, dim3(1), dim3(64), 0, stream,
                       Wih, bih, Whh, bhh, fcw, fcb, ws);
    hipLaunchKernelGGL(garch_main, dim3(1024), dim3(512), 0, stream,
                       res, ws, out);
}

// Round 7
// 190.601 us; speedup vs baseline: 1.4464x; 1.4464x over previous
//
#include <hip/hip_runtime.h>

#define S_LEN 2048

typedef float f32x4 __attribute__((ext_vector_type(4)));

__device__ __forceinline__ float rlane(float v, int l) {
    return __int_as_float(__builtin_amdgcn_readlane(__float_as_int(v), l));
}

template<int CTRL, int RM>
__device__ __forceinline__ float dpp_add(float v) {
    int t = __builtin_amdgcn_update_dpp(0, __float_as_int(v), CTRL, RM, 0xF, true);
    return v + __int_as_float(t);
}
// sum across 64 lanes -> uniform scalar, VALU-only.
__device__ __forceinline__ float wave_sum(float v) {
    v = dpp_add<0x111, 0xF>(v);
    v = dpp_add<0x112, 0xF>(v);
    v = dpp_add<0x114, 0xF>(v);
    v = dpp_add<0x118, 0xF>(v);
    v = dpp_add<0x142, 0xA>(v);
    v = dpp_add<0x143, 0xC>(v);
    return rlane(v, 63);
}
// per-half (32-lane) sum, broadcast to that half's lanes
__device__ __forceinline__ float half_sum(float v, bool hf) {
    v = dpp_add<0x111, 0xF>(v);
    v = dpp_add<0x112, 0xF>(v);
    v = dpp_add<0x114, 0xF>(v);
    v = dpp_add<0x118, 0xF>(v);
    v = dpp_add<0x142, 0xA>(v);   // row_bcast:15 -> lane31/lane63 hold half sums
    const float lo = rlane(v, 31);
    const float hi = rlane(v, 63);
    return hf ? hi : lo;
}

#if __has_builtin(__builtin_amdgcn_exp2f)
#define EXP2F(x) __builtin_amdgcn_exp2f(x)
#else
#define EXP2F(x) exp2f(x)
#endif
#if __has_builtin(__builtin_amdgcn_logf)
#define LOG2F(x) __builtin_amdgcn_logf(x)
#else
#define LOG2F(x) __log2f(x)
#endif

// ============================ setup kernel (1 wave) ============================
// ws layout (floats):
//  [0..1024)    alphaC32 row-major: aC[l*32+j] = (m=(l-j)&31)<4 ? 0 : K*alpha_m
//  [1024..2048) betaC32:            <4 ? 0 : beta_m (TRUE scale)
//  [2048..2080) gpre32[l] = K*Gamma_{l+1}
//  [2080] K*Gamma_inf ; [2081..2085) b0..b3 (true) ; [2085..2089) K*alpha_{0..3}
__global__ __launch_bounds__(64) void garch_setup(
    const float* __restrict__ Wih, const float* __restrict__ bih,
    const float* __restrict__ Whh, const float* __restrict__ bhh,
    const float* __restrict__ fcw, const float* __restrict__ fcb,
    float* __restrict__ ws)
{
    const int lane = threadIdx.x;
    __shared__ __align__(16) float ub[64];
    __shared__ float alpS[32], betS[32];

    float wr[64];
#pragma unroll
    for (int k = 0; k < 64; ++k) wr[k] = Whh[k * 64 + lane];   // W[k][lane]

    const float w0l = Wih[lane * 2], w1l = Wih[lane * 2 + 1];
    const float bl = bih[lane] + bhh[lane];
    const float fl = fcw[lane];
    const float Kc = 1.44269504088896340736f;

    const float A0  = Kc * wave_sum(fl * w0l);
    const float b0t = wave_sum(fl * w1l);
    const float C   = Kc * (wave_sum(fl * bl) + fcb[0]);
    if (lane == 0) { alpS[0] = A0; betS[0] = b0t; }
    float gpre = C, ginf = C;

    ub[lane] = fl;
    asm volatile("" ::: "memory");
    const f32x4* uq4 = (const f32x4*)ub;
    float u;
    {
        float n0 = 0.f, n1 = 0.f, n2 = 0.f, n3 = 0.f;
#pragma unroll
        for (int q = 0; q < 16; ++q) {
            const f32x4 uq = uq4[q];
            n0 = fmaf(wr[4 * q + 0], uq.x, n0);
            n1 = fmaf(wr[4 * q + 1], uq.y, n1);
            n2 = fmaf(wr[4 * q + 2], uq.z, n2);
            n3 = fmaf(wr[4 * q + 3], uq.w, n3);
        }
        u = (n0 + n1) + (n2 + n3);
    }
#pragma unroll 1
    for (int i = 1; i < 48; ++i) {
        const float daK = Kc * wave_sum(u * w0l);
        const float dbT = wave_sum(u * w1l);
        const float dgK = Kc * wave_sum(u * bl);
        if (lane == 0 && i < 32) { alpS[i] = daK; betS[i] = dbT; }
        gpre += (lane >= i) ? dgK : 0.f;
        ginf += dgK;
        ub[lane] = u;
        asm volatile("" ::: "memory");
        float n0 = 0.f, n1 = 0.f, n2 = 0.f, n3 = 0.f;
#pragma unroll
        for (int q = 0; q < 16; ++q) {
            const f32x4 uq = uq4[q];
            n0 = fmaf(wr[4 * q + 0], uq.x, n0);
            n1 = fmaf(wr[4 * q + 1], uq.y, n1);
            n2 = fmaf(wr[4 * q + 2], uq.z, n2);
            n3 = fmaf(wr[4 * q + 3], uq.w, n3);
        }
        u = (n0 + n1) + (n2 + n3);
    }
    asm volatile("" ::: "memory");

    for (int f = lane; f < 1024; f += 64) {
        const int l = f >> 5, j = f & 31;
        const int m = (l - j) & 31;
        ws[f]        = (m < 4) ? 0.f : alpS[m];
        ws[1024 + f] = (m < 4) ? 0.f : betS[m];
    }
    if (lane < 32) ws[2048 + lane] = gpre;
    if (lane == 0) ws[2080] = ginf;
    if (lane < 4) { ws[2081 + lane] = betS[lane]; ws[2085 + lane] = alpS[lane]; }
}

// ============================ main kernel ============================
// 2 rows per wave (lanes 0-31 row A, 32-63 row B), 32-lag window, 32-step chunks.
// Chain ops are per-half-uniform VGPR arithmetic -> each op serves both rows.
// Coefficient circulants in 64 PINNED VGPRs (kills r6's 512B/step LDS stream).
// 4 segments/row-pair, 2 warm-up chunks (64 steps, zero sigma-history; E-side exact
// via FIR + masked circulant from previous chunk -- r6-validated scheme, 64->32).
__attribute__((amdgpu_flat_work_group_size(512, 512)))
__attribute__((amdgpu_waves_per_eu(4, 8)))
__global__ void garch_main(
    const float* __restrict__ res, const float* __restrict__ ws,
    float* __restrict__ out)
{
    __shared__ __align__(16) float ring[1024];   // 8 waves x (2 halves x 64-float ring)

    const int tid  = threadIdx.x;
    const int lane = tid & 63;
    const int wv   = tid >> 6;
    const int l    = lane & 31;
    const bool hf  = (lane >= 32);

    float* __restrict__ ringw = &ring[wv * 128 + (hf ? 64 : 0)];

    // circulant coefficients -> registers (row l of each table), pinned
    const f32x4* wst = (const f32x4*)ws;
    f32x4 ca[8], cb[8];
#pragma unroll
    for (int q = 0; q < 8; ++q) { ca[q] = wst[l * 8 + q]; cb[q] = wst[256 + l * 8 + q]; }
    asm("" : "+v"(ca[0]), "+v"(ca[1]), "+v"(ca[2]), "+v"(ca[3]),
             "+v"(ca[4]), "+v"(ca[5]), "+v"(ca[6]), "+v"(ca[7]),
             "+v"(cb[0]), "+v"(cb[1]), "+v"(cb[2]), "+v"(cb[3]),
             "+v"(cb[4]), "+v"(cb[5]), "+v"(cb[6]), "+v"(cb[7]));

    const float ginf = ws[2080];
    const float b0 = ws[2081], b1 = ws[2082], b2 = ws[2083], b3 = ws[2084];
    const float Ka0 = ws[2085], Ka1 = ws[2086], Ka2 = ws[2087], Ka3 = ws[2088];
    const float Kc  = 1.44269504088896340736f;
    const float LN2 = 0.69314718055994530942f;

    const int gw = blockIdx.x * 8 + wv;      // 0..4095
    const int rp = gw >> 2;                  // row pair
    const int p  = gw & 3;                   // segment
    const float* __restrict__ row  = res + (size_t)(2 * rp + (hf ? 1 : 0)) * S_LEN;
    float* __restrict__       orow = out + (size_t)(2 * rp + (hf ? 1 : 0)) * S_LEN;

    const int rotaddr = ((lane & 32) | ((l + 31) & 31)) << 2;   // within-half rotate-by-1

// 4-tap FIR over the e2 ring: DST[l] = sum_m Ka_m * e2[slot SB, l-m]; (a-m)&63
// wraps into the other slot's tail = previous chunk's last values (both parities).
#define FIR4(DST, SB) { \
    const int a0_ = ((SB) << 5) + l; \
    const float x0_ = ringw[a0_]; \
    const float x1_ = ringw[(a0_ - 1) & 63]; \
    const float x2_ = ringw[(a0_ - 2) & 63]; \
    const float x3_ = ringw[(a0_ - 3) & 63]; \
    (DST) = fmaf(Ka3, x3_, fmaf(Ka2, x2_, fmaf(Ka1, x1_, Ka0 * x0_))); }

// per-half broadcast of V's lane IDX (and 32+IDX)
#define BCASTI(DST, V, IDX) { \
    const float lo_ = rlane((V), (IDX)); \
    const float hi_ = rlane((V), 32 + (IDX)); \
    (DST) = hf ? hi_ : lo_; }

    float acc, sigK, carry, p1, p2, p3, ldn, varh = 0.f;
    float vout = 0.f;
    int c0w, warm;

    if (p == 0) {
        // sigma0 = var(row, ddof=1), per half
        float s1 = 0.f, s2 = 0.f;
#pragma unroll 8
        for (int i = 0; i < 64; ++i) {
            const float x = row[i * 32 + l];
            s1 += x;
            s2 = fmaf(x, x, s2);
        }
        s1 = half_sum(s1, hf);
        s2 = half_sum(s2, hf);
        const float mean = s1 * (1.0f / S_LEN);
        varh = (s2 - s1 * mean) * (1.0f / (S_LEN - 1));
        sigK = Kc * varh;
        carry = sigK;

        const float e0 = row[l], e1 = row[32 + l];
        ringw[l] = e0 * e0;          // slot0 = e2(chunk 0)
        ringw[32 + l] = 0.f;         // zero boundary for FIR(chunk 0)
        asm volatile("" ::: "memory");
        float e4C;
        FIR4(e4C, 0);
        acc = ws[2048 + l] + e4C;    // gpre32 + FIR lags 0..3
        BCASTI(p1, acc, 0); BCASTI(p2, acc, 1); BCASTI(p3, acc, 2);
        ringw[32 + l] = e1 * e1;     // slot1 = e2(chunk 1)
        asm volatile("" ::: "memory");
        ldn = row[64 + l];           // raw chunk 2
        c0w = 0; warm = 0;
    } else {
        const int cw0 = p * 16 - 2;  // first warm-up chunk
        const float eP = row[(cw0 - 1) * 32 + l];
        const float eC = row[cw0 * 32 + l];
        const float eN = row[(cw0 + 1) * 32 + l];
        ringw[((cw0 - 1) & 1) * 32 + l] = eP * eP;
        ringw[(cw0 & 1) * 32 + l]       = eC * eC;
        asm volatile("" ::: "memory");
        float e4C;
        FIR4(e4C, cw0 & 1);          // boundary taps from e2(cw0-1) via ring wrap
        acc = ginf + e4C;
        // exact alpha wrap-init from chunk cw0-1 (lags l+1..31; <4 zeroed -> FIR covers)
        const f32x4* pq = (const f32x4*)(ringw + ((cw0 - 1) & 1) * 32);
#pragma unroll
        for (int q = 0; q < 8; ++q) {
            const f32x4 eq = pq[q];
#pragma unroll
            for (int w = 0; w < 4; ++w) {
                const int j = 4 * q + w;
                const float cf = (j > l) ? ca[q][w] : 0.f;
                acc = fmaf(cf, eq[w], acc);
            }
        }
        BCASTI(p1, acc, 0); BCASTI(p2, acc, 1); BCASTI(p3, acc, 2);
        sigK = 0.f; carry = 0.f;     // zero sigma-history (decays over 64 warm steps)
        ringw[((cw0 + 1) & 1) * 32 + l] = eN * eN;   // overwrite after masked reads
        asm volatile("" ::: "memory");
        ldn = row[(cw0 + 2) * 32 + l];
        c0w = cw0; warm = 2;
    }

    const int ncc = 16 + warm;
    const bool p0 = (p == 0);

#pragma unroll 1
    for (int cc = 0; cc < ncc; ++cc) {
        const int c = c0w + cc;
        const int s = c & 1;
        float e4N;
        FIR4(e4N, s ^ 1);            // FIR(chunk c+1); boundary from slot s tail
        const float sigchunk = carry;

        const f32x4* ringq = (const f32x4*)(ringw + (s << 5));
        f32x4 curA = ringq[0], curB = ringq[1];
        f32x4 nxtA, nxtB;

#pragma unroll
        for (int jg = 0; jg < 4; ++jg) {
            if (jg < 3) { nxtA = ringq[(jg + 1) * 2]; nxtB = ringq[(jg + 1) * 2 + 1]; }
#pragma unroll
            for (int k = 0; k < 8; ++k) {
                const int jj = jg * 8 + k;
                const float ash = ca[jj >> 2][jj & 3];      // K*alpha'_{(l-jj)&31}
                const float bsh = cb[jj >> 2][jj & 3];      // beta'_{(l-jj)&31}
                const float e2j = (k < 4) ? curA[k] : curB[k - 4];
                const float xp = fmaf(b0, sigK, p1);        // on-chain (K-scaled)
                acc = fmaf(bsh, sigK, acc);                 // sigma lags >=4 (wrap -> next)
                acc = fmaf(ash, e2j, acc);                  // e2 lags >=4 (wrap -> next)
                const bool mine = (l == jj);
                acc = mine ? ginf : acc;                    // reset-at-consume
                const float tlo = rlane(acc, (jj + 3) & 31);
                const float thi = rlane(acc, 32 + ((jj + 3) & 31));
                float t = hf ? thi : tlo;                   // hoisted-3 read, per half
                if (jj >= 29) {                             // wrapped reads: +FIR(c+1)
                    const float clo = rlane(e4N, jj - 29);
                    const float chi = rlane(e4N, 32 + (jj - 29));
                    t += hf ? chi : clo;
                }
                p1 = fmaf(b1, sigK, p2);
                p2 = fmaf(b2, sigK, p3);
                p3 = fmaf(b3, sigK, t);
                const float ee = EXP2F(-__builtin_fabsf(xp));
                sigK = fmaxf(xp, 0.f) + LOG2F(1.0f + ee);   // log2-domain softplus
                vout = mine ? sigK : vout;                  // lane jj: sigma_{32c+jj+1}
            }
            if (jg < 3) { curA = nxtA; curB = nxtB; }
        }

        if (cc >= warm) {
            const float rotv = __int_as_float(
                __builtin_amdgcn_ds_bpermute(rotaddr, __float_as_int(vout)));
            const float sv = (l == 0) ? sigchunk : rotv;
            float outv = fmaf(sv, LN2, 1e-6f);
            if (p0 && cc == 0) outv = (l == 0) ? varh : outv;   // t=0: exact variance
            orow[(c << 5) + l] = outv;
        }
        {
            const float c1v = rlane(vout, 31);
            const float c2v = rlane(vout, 63);
            carry = hf ? c2v : c1v;                          // sigma_{32(c+1)}, per half
        }
        acc += e4N;                                          // boundary fold
        ringw[(s << 5) + l] = ldn * ldn;                     // slot s <- e2(c+2)
        const int nc3 = (c + 3 < 63) ? (c + 3) : 63;
        ldn = row[nc3 * 32 + l];
        asm volatile("" ::: "memory");
    }
#undef FIR4
#undef BCASTI
}

extern "C" void kernel_launch(void* const* d_in, const int* in_sizes, int n_in,
                              void* d_out, int out_size, void* d_ws, size_t ws_size,
                              hipStream_t stream) {
    const float* res = (const float*)d_in[0];
    const float* Wih = (const float*)d_in[1];
    const float* bih = (const float*)d_in[2];
    const float* Whh = (const float*)d_in[3];
    const float* bhh = (const float*)d_in[4];
    const float* fcw = (const float*)d_in[5];
    const float* fcb = (const float*)d_in[6];
    float* out = (float*)d_out;
    float* ws  = (float*)d_ws;

    hipLaunchKernelGGL(garch_setup, dim3(1), dim3(64), 0, stream,
                       Wih, bih, Whh, bhh, fcw, fcb, ws);
    hipLaunchKernelGGL(garch_main, dim3(512), dim3(512), 0, stream,
                       res, ws, out);
}

// Round 8
// 188.983 us; speedup vs baseline: 1.4588x; 1.0086x over previous
//
#include <hip/hip_runtime.h>

#define S_LEN 2048

typedef float f32x4 __attribute__((ext_vector_type(4)));

__device__ __forceinline__ float rlane(float v, int l) {
    return __int_as_float(__builtin_amdgcn_readlane(__float_as_int(v), l));
}

template<int CTRL, int RM>
__device__ __forceinline__ float dpp_add(float v) {
    int t = __builtin_amdgcn_update_dpp(0, __float_as_int(v), CTRL, RM, 0xF, true);
    return v + __int_as_float(t);
}
// sum across 64 lanes -> uniform scalar, VALU-only.
__device__ __forceinline__ float wave_sum(float v) {
    v = dpp_add<0x111, 0xF>(v);
    v = dpp_add<0x112, 0xF>(v);
    v = dpp_add<0x114, 0xF>(v);
    v = dpp_add<0x118, 0xF>(v);
    v = dpp_add<0x142, 0xA>(v);
    v = dpp_add<0x143, 0xC>(v);
    return rlane(v, 63);
}
// per-half (32-lane) sum, broadcast to that half's lanes
__device__ __forceinline__ float half_sum(float v, bool hf) {
    v = dpp_add<0x111, 0xF>(v);
    v = dpp_add<0x112, 0xF>(v);
    v = dpp_add<0x114, 0xF>(v);
    v = dpp_add<0x118, 0xF>(v);
    v = dpp_add<0x142, 0xA>(v);   // lane31/lane63 hold the two half sums
    const float lo = rlane(v, 31);
    const float hi = rlane(v, 63);
    return hf ? hi : lo;
}

#if __has_builtin(__builtin_amdgcn_exp2f)
#define EXP2F(x) __builtin_amdgcn_exp2f(x)
#else
#define EXP2F(x) exp2f(x)
#endif
#if __has_builtin(__builtin_amdgcn_logf)
#define LOG2F(x) __builtin_amdgcn_logf(x)
#else
#define LOG2F(x) __log2f(x)
#endif

// Fused single-kernel version (r8):
//  - per-block setup (wave 0): u-chain matvec reads Whh from LDS (no wr[64]
//    register array -> VGPR stays <=64); writes 32-lag circulant tables to LDS.
//  - P=8 segments/row (1 warm-up chunk of 32 steps; error decay ~0.6^32 ~ 5e-8),
//    8192 waves -> 8 waves/SIMD (was 4, latency-bound).
//  - coefficient quads streamed from LDS per 8-step group (512 B/step/wave;
//    at 32 waves/CU = 128 cy/group vs ~350 cy issue -> not the wall), freeing
//    the 64-register coefficient block of r7.
//  - FIR(c+1) delivered via the per-chunk reset value (acc = mine ? ginf+e4N : acc):
//    hand-verified equivalent to r7's end-fold + jj>=29 corrections (the m<4
//    zeroing of the circulants prevents any double-count).
__attribute__((amdgpu_flat_work_group_size(512, 512)))
__attribute__((amdgpu_waves_per_eu(8)))
__global__ void garch_fused(
    const float* __restrict__ res,   // (B, S)
    const float* __restrict__ Wih,   // (64, 2)
    const float* __restrict__ bih,   // (64,)
    const float* __restrict__ Whh,   // (64, 64)
    const float* __restrict__ bhh,   // (64,)
    const float* __restrict__ fcw,   // (64,)
    const float* __restrict__ fcb,   // (1,)
    float* __restrict__ out)         // (B, S)
{
    __shared__ __align__(16) float Wl[4096];     // staged Whh (setup only)
    __shared__ __align__(16) float tabA[1024];   // quad-major K*alpha circulant
    __shared__ __align__(16) float tabB[1024];   // quad-major TRUE-beta circulant
    __shared__ __align__(16) float ring[1024];   // 8 waves x 2 halves x 64 e2 ring
    __shared__ __align__(16) float ubuf[64];
    __shared__ float alpS[32], betS[32], gpreS[32], scS[4];

    const int tid  = threadIdx.x;
    const int lane = tid & 63;
    const int wv   = tid >> 6;
    const int l    = lane & 31;
    const bool hf  = (lane >= 32);

    const float Kc  = 1.44269504088896340736f;
    const float LN2 = 0.69314718055994530942f;

    // ---- cooperative stage Whh -> LDS ----
    {
        const f32x4* w4 = (const f32x4*)Whh;
        f32x4* wl4 = (f32x4*)Wl;
        for (int i = tid; i < 1024; i += 512) wl4[i] = w4[i];
    }
    __syncthreads();

    // ---- wave 0: u-chain + table build (LDS-sourced matvec, low VGPR) ----
    if (wv == 0) {
        const float w0l = Wih[lane * 2], w1l = Wih[lane * 2 + 1];
        const float blp = bih[lane] + bhh[lane];
        const float fl  = fcw[lane];

        const float A0  = Kc * wave_sum(fl * w0l);
        const float b0t = wave_sum(fl * w1l);
        const float Cg  = Kc * (wave_sum(fl * blp) + fcb[0]);
        if (lane == 0) { alpS[0] = A0; betS[0] = b0t; }
        float gpre_ = Cg, ginf_ = Cg;

        ubuf[lane] = fl;
        asm volatile("" ::: "memory");
        const f32x4* uq4 = (const f32x4*)ubuf;
        float u;
        {
            float n0 = 0.f, n1 = 0.f, n2 = 0.f, n3 = 0.f;
#pragma unroll 4
            for (int q = 0; q < 16; ++q) {      // LDS-indexed: no register array
                const f32x4 uq = uq4[q];
                n0 = fmaf(Wl[(4 * q + 0) * 64 + lane], uq.x, n0);
                n1 = fmaf(Wl[(4 * q + 1) * 64 + lane], uq.y, n1);
                n2 = fmaf(Wl[(4 * q + 2) * 64 + lane], uq.z, n2);
                n3 = fmaf(Wl[(4 * q + 3) * 64 + lane], uq.w, n3);
            }
            u = (n0 + n1) + (n2 + n3);
        }
#pragma unroll 1
        for (int i = 1; i < 48; ++i) {
            const float daK = Kc * wave_sum(u * w0l);
            const float dbT = wave_sum(u * w1l);        // TRUE beta_i
            const float dgK = Kc * wave_sum(u * blp);   // K*g_{i-1}
            if (lane == 0 && i < 32) { alpS[i] = daK; betS[i] = dbT; }
            gpre_ += (lane >= i) ? dgK : 0.f;
            ginf_ += dgK;
            ubuf[lane] = u;
            asm volatile("" ::: "memory");
            float n0 = 0.f, n1 = 0.f, n2 = 0.f, n3 = 0.f;
#pragma unroll 4
            for (int q = 0; q < 16; ++q) {
                const f32x4 uq = uq4[q];
                n0 = fmaf(Wl[(4 * q + 0) * 64 + lane], uq.x, n0);
                n1 = fmaf(Wl[(4 * q + 1) * 64 + lane], uq.y, n1);
                n2 = fmaf(Wl[(4 * q + 2) * 64 + lane], uq.z, n2);
                n3 = fmaf(Wl[(4 * q + 3) * 64 + lane], uq.w, n3);
            }
            u = (n0 + n1) + (n2 + n3);
        }
        asm volatile("" ::: "memory");
        // quad-major tables: tab[(q*32 + l)*4 + w] = T[l][4q+w], lags<4 zeroed
        for (int f = lane; f < 1024; f += 64) {
            const int lr = f >> 5, jc = f & 31;
            const int m = (lr - jc) & 31;
            const int dst = (((jc >> 2) * 32 + lr) << 2) + (jc & 3);
            tabA[dst] = (m < 4) ? 0.f : alpS[m];
            tabB[dst] = (m < 4) ? 0.f : betS[m];
        }
        if (lane < 32) gpreS[lane] = gpre_;
        if (lane == 0) scS[0] = ginf_;
    }
    __syncthreads();

    // ---- per-wave segment decode ----
    const float ginf = scS[0];
    const float bb0 = betS[0], bb1 = betS[1], bb2 = betS[2], bb3 = betS[3];
    const float Ka0 = alpS[0], Ka1 = alpS[1], Ka2 = alpS[2], Ka3 = alpS[3];

    const int rp = blockIdx.x;               // row pair
    const int p  = wv;                       // segment 0..7 (8 chunks each)
    const float* __restrict__ row  = res + (size_t)(2 * rp + (hf ? 1 : 0)) * S_LEN;
    float* __restrict__       orow = out + (size_t)(2 * rp + (hf ? 1 : 0)) * S_LEN;

    float* __restrict__ ringw = &ring[wv * 128 + (hf ? 64 : 0)];
    const int rotaddr = ((lane & 32) | ((l + 31) & 31)) << 2;

#define FIR4(DST, SB) { \
    const int a0_ = ((SB) << 5) + l; \
    const float x0_ = ringw[a0_]; \
    const float x1_ = ringw[(a0_ - 1) & 63]; \
    const float x2_ = ringw[(a0_ - 2) & 63]; \
    const float x3_ = ringw[(a0_ - 3) & 63]; \
    (DST) = fmaf(Ka3, x3_, fmaf(Ka2, x2_, fmaf(Ka1, x1_, Ka0 * x0_))); }

#define BCASTI(DST, V, IDX) { \
    const float lo_ = rlane((V), (IDX)); \
    const float hi_ = rlane((V), 32 + (IDX)); \
    (DST) = hf ? hi_ : lo_; }

    const f32x4* tA4 = (const f32x4*)tabA;
    const f32x4* tB4 = (const f32x4*)tabB;

    float acc, sigK, carry, p1, p2, p3, ldn, varh = 0.f;
    float vout = 0.f;
    int c0w, warm;

    if (p == 0) {
        // sigma0 = var(row, ddof=1), per half
        float s1 = 0.f, s2 = 0.f;
#pragma unroll 8
        for (int i = 0; i < 64; ++i) {
            const float x = row[i * 32 + l];
            s1 += x;
            s2 = fmaf(x, x, s2);
        }
        s1 = half_sum(s1, hf);
        s2 = half_sum(s2, hf);
        const float mean = s1 * (1.0f / S_LEN);
        varh = (s2 - s1 * mean) * (1.0f / (S_LEN - 1));
        sigK = Kc * varh;
        carry = sigK;

        const float e0 = row[l], e1 = row[32 + l];
        ringw[l] = e0 * e0;          // slot0 = e2(0)
        ringw[32 + l] = 0.f;         // e2(-1) = 0 boundary for FIR(0)
        asm volatile("" ::: "memory");
        float e4C;
        FIR4(e4C, 0);
        acc = gpreS[l] + e4C;        // K*Gamma_{l+1} + FIR lags 0..3 of chunk 0
        BCASTI(p1, acc, 0); BCASTI(p2, acc, 1); BCASTI(p3, acc, 2);
        ringw[32 + l] = e1 * e1;     // slot1 = e2(1)
        asm volatile("" ::: "memory");
        ldn = row[64 + l];           // raw chunk 2
        c0w = 0; warm = 0;
    } else {
        const int cw0 = 8 * p - 1;   // warm-up chunk (odd)
        const float eP = row[(cw0 - 1) * 32 + l];
        const float eC = row[cw0 * 32 + l];
        const float eN = row[(cw0 + 1) * 32 + l];
        ringw[((cw0 - 1) & 1) * 32 + l] = eP * eP;
        ringw[(cw0 & 1) * 32 + l]       = eC * eC;
        asm volatile("" ::: "memory");
        float e4C;
        FIR4(e4C, cw0 & 1);          // FIR(cw0); boundary from e2(cw0-1)
        acc = ginf + e4C;
        // exact alpha wrap-init from chunk cw0-1 (lags l+1..31)
        const f32x4* pq = (const f32x4*)(ringw + ((cw0 - 1) & 1) * 32);
#pragma unroll
        for (int q = 0; q < 8; ++q) {
            const f32x4 aqv = tA4[q * 32 + l];
            const f32x4 eq = pq[q];
#pragma unroll
            for (int w = 0; w < 4; ++w) {
                const int j = 4 * q + w;
                const float cf = (j > l) ? aqv[w] : 0.f;
                acc = fmaf(cf, eq[w], acc);
            }
        }
        BCASTI(p1, acc, 0); BCASTI(p2, acc, 1); BCASTI(p3, acc, 2);
        sigK = 0.f; carry = 0.f;     // zero sigma-history: decays over 32 warm steps
        ringw[((cw0 + 1) & 1) * 32 + l] = eN * eN;
        asm volatile("" ::: "memory");
        ldn = row[(cw0 + 2) * 32 + l];
        c0w = cw0; warm = 1;
    }

    const int ncc = 8 + warm;
    const bool p0 = (p == 0);

#pragma unroll 1
    for (int cc = 0; cc < ncc; ++cc) {
        const int c = c0w + cc;
        const int s = c & 1;
        float e4N;
        FIR4(e4N, s ^ 1);                    // FIR(chunk c+1)
        const float ginfE = ginf + e4N;      // reset value carries FIR(c+1)
        const float sigchunk = carry;
        const f32x4* ringq = (const f32x4*)(ringw + (s << 5));

#pragma unroll
        for (int jg = 0; jg < 4; ++jg) {
            const f32x4 caq0 = tA4[(2 * jg) * 32 + l];
            const f32x4 caq1 = tA4[(2 * jg + 1) * 32 + l];
            const f32x4 cbq0 = tB4[(2 * jg) * 32 + l];
            const f32x4 cbq1 = tB4[(2 * jg + 1) * 32 + l];
            const f32x4 curA = ringq[jg * 2];
            const f32x4 curB = ringq[jg * 2 + 1];
#pragma unroll
            for (int k = 0; k < 8; ++k) {
                const int jj = (jg << 3) + k;
                const float ash = (k < 4) ? caq0[k] : caq1[k - 4];
                const float bsh = (k < 4) ? cbq0[k] : cbq1[k - 4];
                const float e2j = (k < 4) ? curA[k] : curB[k - 4];
                const float xp = fmaf(bb0, sigK, p1);     // on-chain
                acc = fmaf(bsh, sigK, acc);               // sigma lags >=4
                acc = fmaf(ash, e2j, acc);                // e2 lags >=4
                const bool mine = (l == jj);
                acc = mine ? ginfE : acc;                 // reset (incl. FIR(c+1))
                const float tlo = rlane(acc, (jj + 3) & 31);
                const float thi = rlane(acc, 32 + ((jj + 3) & 31));
                const float t = hf ? thi : tlo;           // hoisted-3 read, per half
                p1 = fmaf(bb1, sigK, p2);
                p2 = fmaf(bb2, sigK, p3);
                p3 = fmaf(bb3, sigK, t);
                const float ee = EXP2F(-__builtin_fabsf(xp));
                sigK = fmaxf(xp, 0.f) + LOG2F(1.0f + ee); // log2-domain softplus
                vout = mine ? sigK : vout;                // lane jj: sigma_{32c+jj+1}
            }
        }

        if (cc >= warm) {
            const float rotv = __int_as_float(
                __builtin_amdgcn_ds_bpermute(rotaddr, __float_as_int(vout)));
            const float sv = (l == 0) ? sigchunk : rotv;
            float outv = fmaf(sv, LN2, 1e-6f);
            if (p0 && cc == 0) outv = (l == 0) ? varh : outv;   // t=0: exact variance
            orow[(c << 5) + l] = outv;
        }
        {
            const float c1v = rlane(vout, 31);
            const float c2v = rlane(vout, 63);
            carry = hf ? c2v : c1v;
        }
        ringw[(s << 5) + l] = ldn * ldn;     // slot s <- e2(c+2)
        const int nc3 = (c + 3 < 63) ? (c + 3) : 63;
        ldn = row[nc3 * 32 + l];
        asm volatile("" ::: "memory");
    }
#undef FIR4
#undef BCASTI
}

extern "C" void kernel_launch(void* const* d_in, const int* in_sizes, int n_in,
                              void* d_out, int out_size, void* d_ws, size_t ws_size,
                              hipStream_t stream) {
    const float* res = (const float*)d_in[0];
    const float* Wih = (const float*)d_in[1];
    const float* bih = (const float*)d_in[2];
    const float* Whh = (const float*)d_in[3];
    const float* bhh = (const float*)d_in[4];
    const float* fcw = (const float*)d_in[5];
    const float* fcb = (const float*)d_in[6];
    float* out = (float*)d_out;

    hipLaunchKernelGGL(garch_fused, dim3(1024), dim3(512), 0, stream,
                       res, Wih, bih, Whh, bhh, fcw, fcb, out);
}